// Round 1
// 2481.291 us; speedup vs baseline: 1.3937x; 1.3937x over previous
//
#include <hip/hip_runtime.h>

#define HD 1024
#define VOC 32000
#define SL 64
#define TL 64
#define NWG 256
#define BLK 256

// sentinel NaN used for dataflow sync; never produced by the math
// (h = sigm*tanh in (-1,1); pe bounded sums of v*tanh)
#define SENT 0x7FC0DEADu

// ---- workspace float offsets ----
// [0..64): barrier words (zeroed by hipMemsetAsync each launch)
#define OFF_HCH    4096      // h chain [129][1024]: enc h_t at slot t (slot 0 unused: h0==0), dec h at 64+t, ends 136192
#define OFF_EPT    139264    // epT [1024][64]  (enc_proj transposed), ends 204800
#define OFF_WIHX   204800    // WihX [64][4096] (enc phase) -- region reused as pe chain [64][4096] (dec phase), ends 466944
#define OFF_PE     OFF_WIHX
#define OFF_Q      466944    // Q    [64][4096], ends 729088
#define OFF_M1     729088    // M1   [64][1024], ends 794624
#define OFF_M2     794624    // M2T  [64][4096], ends 1056768
#define OFF_PRET   1056768   // PreT [1024][64], ends 1122304
#define OFF_XENC   1122304   // Xenc [64][1024]
#define OFF_XDEC   1187840   // Xdec [64][1024]
#define OFF_PRE1   1253376   // pre1 [64][1024], ends 1318912 (same extent as previous version)

struct KArgs {
  const int* src; const int* tgt;
  const void *enc_emb, *enc_Wih, *enc_Whh, *enc_bih, *enc_bhh;
  const void *dec_emb, *att_We, *att_be, *att_Wu, *att_bu, *att_v;
  const void *w1_W, *w1_b, *w2_W, *w2_b;
  const void *dec_Wih, *dec_Whh, *dec_bih, *dec_bhh;
  const void *out_W, *out_b;
  void* out; float* ws;
};

__device__ __forceinline__ float bf2f(unsigned short u) {
  unsigned w = ((unsigned)u) << 16; float f; __builtin_memcpy(&f, &w, 4); return f;
}
__device__ __forceinline__ unsigned short f2bf(float f) {
  unsigned u; __builtin_memcpy(&u, &f, 4);
  unsigned r = u + 0x7FFFu + ((u >> 16) & 1u);
  return (unsigned short)(r >> 16);
}
__device__ __forceinline__ float sigmf(float x) { return 1.f / (1.f + expf(-x)); }

// MALL-coherent (cross-XCD) relaxed accesses for all workspace traffic.
__device__ __forceinline__ float ldw(const float* p) {
  return __hip_atomic_load(p, __ATOMIC_RELAXED, __HIP_MEMORY_SCOPE_AGENT);
}
__device__ __forceinline__ void stw(float* p, float v) {
  __hip_atomic_store(p, v, __ATOMIC_RELAXED, __HIP_MEMORY_SCOPE_AGENT);
}
__device__ __forceinline__ unsigned ldu(const unsigned* p) {
  return __hip_atomic_load(p, __ATOMIC_RELAXED, __HIP_MEMORY_SCOPE_AGENT);
}
__device__ __forceinline__ void stu(unsigned* p, unsigned v) {
  __hip_atomic_store(p, v, __ATOMIC_RELAXED, __HIP_MEMORY_SCOPE_AGENT);
}

struct BFT {}; struct FPT {};
template<class DT> struct LD;
template<> struct LD<FPT> {
  static __device__ __forceinline__ float get(const void* p, long i) { return ((const float*)p)[i]; }
};
template<> struct LD<BFT> {
  static __device__ __forceinline__ float get(const void* p, long i) { return bf2f(((const unsigned short*)p)[i]); }
};
template<class DT> struct LD4;
template<> struct LD4<FPT> {
  static __device__ __forceinline__ float4 get(const void* p, long i) {
    return *(const float4*)((const float*)p + i);
  }
};
template<> struct LD4<BFT> {
  static __device__ __forceinline__ float4 get(const void* p, long i) {
    ushort4 u = *(const ushort4*)((const unsigned short*)p + i);
    float4 f; f.x = bf2f(u.x); f.y = bf2f(u.y); f.z = bf2f(u.z); f.w = bf2f(u.w); return f;
  }
};
template<class DT> struct ST;
template<> struct ST<FPT> {
  static __device__ __forceinline__ void put(void* p, long i, float v) { ((float*)p)[i] = v; }
};
template<> struct ST<BFT> {
  static __device__ __forceinline__ void put(void* p, long i, float v) { ((unsigned short*)p)[i] = f2bf(v); }
};

// ---- tree grid barrier (only used at phase transitions now; 5 calls total) ----
__device__ __forceinline__ void gbar(unsigned* ws_u, unsigned* ep, int tid, int wg) {
  __syncthreads();
  if (tid == 0) {
    unsigned e = ++(*ep);
    unsigned old = __hip_atomic_fetch_add(&ws_u[8 + (wg >> 5)], 1u,
                                          __ATOMIC_RELAXED, __HIP_MEMORY_SCOPE_AGENT);
    if (old == e * 32u - 1u) {
      unsigned o2 = __hip_atomic_fetch_add(&ws_u[16], 1u,
                                           __ATOMIC_RELAXED, __HIP_MEMORY_SCOPE_AGENT);
      if (o2 == e * 8u - 1u) {
        __hip_atomic_store(&ws_u[20], e, __ATOMIC_RELAXED, __HIP_MEMORY_SCOPE_AGENT);
      }
    }
    while (__hip_atomic_load(&ws_u[20], __ATOMIC_RELAXED, __HIP_MEMORY_SCOPE_AGENT) < e) {
      __builtin_amdgcn_s_sleep(2);
    }
  }
  __syncthreads();
}

// out[t][r] (or [r][t] if TRO) = sum_k W[r*wstride+woff+k] (+ woff2 half if DUAL) * X[t*HD+k] (+biases)
template<class DT, int NR, bool DUAL, bool TRO>
__device__ void gemm_rows(const void* W, int wstride, int woff, int woff2,
                          int r0, const float* X, float* out, int ostride,
                          const void* b1, const void* b2, int tid, float* s_stage) {
  const int PER = NR / 4;
  float acc[PER];
#pragma unroll
  for (int i = 0; i < PER; ++i) acc[i] = 0.f;
  for (int k0 = 0; k0 < HD; k0 += 128) {
    __syncthreads();
    for (int i = tid; i < 64 * 128; i += BLK) {
      int t = i >> 7, kk = i & 127;
      s_stage[t * 129 + kk] = ldw(&X[t * HD + k0 + kk]);
    }
    __syncthreads();
#pragma unroll
    for (int i = 0; i < PER; ++i) {
      int oi = tid + i * BLK;
      int t = oi & 63, r_l = oi >> 6;
      long r = r0 + r_l;
      long wb = r * wstride + woff + k0;
      long wb2 = r * wstride + woff2 + k0;
      float a = 0.f;
#pragma unroll 8
      for (int kk = 0; kk < 128; kk += 4) {
        float4 wv = LD4<DT>::get(W, wb + kk);
        if (DUAL) {
          float4 w2 = LD4<DT>::get(W, wb2 + kk);
          wv.x += w2.x; wv.y += w2.y; wv.z += w2.z; wv.w += w2.w;
        }
        a += wv.x * s_stage[t * 129 + kk]     + wv.y * s_stage[t * 129 + kk + 1]
           + wv.z * s_stage[t * 129 + kk + 2] + wv.w * s_stage[t * 129 + kk + 3];
      }
      acc[i] += a;
    }
  }
  __syncthreads();
#pragma unroll
  for (int i = 0; i < PER; ++i) {
    int oi = tid + i * BLK;
    int t = oi & 63, r_l = oi >> 6;
    int r = r0 + r_l;
    float v = acc[i];
    if (b1) v += LD<DT>::get(b1, r);
    if (b2) v += LD<DT>::get(b2, r);
    if (TRO) stw(&out[r * ostride + t], v); else stw(&out[t * ostride + r], v);
  }
}

template<class DT>
__device__ void run_all(const KArgs& A, int tid, int wg,
                        float* s_big, float* s_red, float* s_w, float* s_m2,
                        float* s_h, float* s_whh, float* s_wh, float* s_gate, float* s_c,
                        float* s_wx, float* s_q, float* s_ep, float* s_av) {
  float* ws = A.ws;
  unsigned* ws_u = (unsigned*)ws;
  unsigned epoch = 0;
  float* hch   = ws + OFF_HCH;
  float* epT   = ws + OFF_EPT;
  float* WihX  = ws + OFF_WIHX;
  float* peC   = ws + OFF_PE;     // same region as WihX; only valid in decoder phase
  float* Q     = ws + OFF_Q;
  float* M1    = ws + OFF_M1;
  float* M2T   = ws + OFF_M2;
  float* PreT  = ws + OFF_PRET;
  float* Xenc  = ws + OFF_XENC;
  float* Xdec  = ws + OFF_XDEC;
  float* pre1  = ws + OFF_PRE1;
  const int j0 = wg * 4;

  // ---- P0a: sentinel-fill h chain, embedding gathers, zero c ----
  if (tid < 4) s_c[tid] = 0.f;
  {
    unsigned* hu = (unsigned*)hch;
    for (int i = wg * BLK + tid; i < 129 * 1024; i += NWG * BLK) stu(hu + i, SENT);
  }
  if (wg < 64) {
    int t = wg, tok = A.src[t];
    for (int k = tid; k < HD; k += BLK) stw(&Xenc[t * HD + k], LD<DT>::get(A.enc_emb, (long)tok * HD + k));
  } else if (wg < 128) {
    int t = wg - 64;
    int tok = (t == 0) ? 0 : A.tgt[t - 1];
    for (int k = tid; k < HD; k += BLK) stw(&Xdec[t * HD + k], LD<DT>::get(A.dec_emb, (long)tok * HD + k));
  }
  gbar(ws_u, &epoch, tid, wg);

  // ---- P0b: WihX (enc_Wih@x + bih + bhh), pre1 (W1x@x + w1_b) ----
  gemm_rows<DT, 16, false, false>(A.enc_Wih, 1024, 0, 0, wg * 16, Xenc, WihX, 4096,
                                  A.enc_bih, A.enc_bhh, tid, s_big);
  gemm_rows<DT, 4, false, false>(A.w1_W, 2048, 1024, 0, wg * 4, Xdec, pre1, 1024,
                                 A.w1_b, nullptr, tid, s_big);
  gbar(ws_u, &epoch, tid, wg);

  // ---- preload this WG's 16 WihX rows x 64 t into LDS (WihX never read again) ----
  for (int i = tid; i < 1024; i += BLK) {
    int t = i >> 4, l = i & 15;
    s_wx[i] = ldw(&WihX[t * 4096 + ((l >> 2) << 10) + j0 + (l & 3)]);
  }

  // ---- encoder loop: NO grid barriers; h[t+1] words polled directly (sentinel) ----
  const int row_l = tid >> 4, lane = tid & 15;
  const int gg_ = row_l >> 2, qq_ = row_l & 3;
  const int myrow = gg_ * 1024 + j0 + qq_;
  for (int t = 0; t < SL; ++t) {
    if (t == 0) {
      for (int i = tid; i < HD; i += BLK) s_h[i] = 0.f;
    } else {
      const unsigned* hb = (const unsigned*)(hch + (size_t)t * HD);
      unsigned uu[4];
#pragma unroll
      for (int j = 0; j < 4; ++j) uu[j] = ldu(hb + tid + j * BLK);
#pragma unroll
      for (int j = 0; j < 4; ++j) {
        while (uu[j] == SENT) { __builtin_amdgcn_s_sleep(1); uu[j] = ldu(hb + tid + j * BLK); }
        float f; __builtin_memcpy(&f, &uu[j], 4);
        s_h[tid + j * BLK] = f;
      }
    }
    __syncthreads();
    float part = 0.f;
#pragma unroll 4
    for (int j = 0; j < 16; ++j) {
      int k = (lane << 2) + (j << 6);
      float4 wv = LD4<DT>::get(A.enc_Whh, (long)myrow * HD + k);
      const float4 hv = *(const float4*)(s_h + k);
      part += wv.x * hv.x + wv.y * hv.y + wv.z * hv.z + wv.w * hv.w;
    }
    s_red[tid] = part;
    __syncthreads();
    if (tid < 16) {
      float v = 0.f;
      for (int i = 0; i < 16; ++i) v += s_red[tid * 16 + i];
      s_gate[tid] = v + s_wx[t * 16 + tid];
    }
    __syncthreads();
    if (tid < 4) {
      float ig = s_gate[tid], fg = s_gate[4 + tid], gv = s_gate[8 + tid], og = s_gate[12 + tid];
      float c2 = sigmf(fg) * s_c[tid] + sigmf(ig) * tanhf(gv);
      float h2v = sigmf(og) * tanhf(c2);
      s_c[tid] = c2;
      stw(&hch[(size_t)(t + 1) * HD + j0 + tid], h2v);
    }
    // no barrier: next iteration's poll IS the synchronization
  }

  // ---- P1ab: epT = (att_Wu@enc_outs + bu)^T ; M1[s][j] = W1c[j].enc_outs[s] ----
  // enc_outs == h chain slots 1..64 (verified-arrived by this WG's own polls)
  gemm_rows<DT, 4, false, true>(A.att_Wu, 1024, 0, 0, wg * 4, hch + HD, epT, 64,
                                A.att_bu, nullptr, tid, s_big);
  gemm_rows<DT, 4, false, false>(A.w1_W, 2048, 0, 0, wg * 4, hch + HD, M1, 1024,
                                 nullptr, nullptr, tid, s_big);
  // sentinel-fill pe chain (reuses WihX region; WihX fully consumed before enc loop exit)
  {
    unsigned* pu = (unsigned*)peC;
    for (int i = tid; i < 1024; i += BLK) stu(pu + wg * 1024 + i, SENT);
  }
  gbar(ws_u, &epoch, tid, wg);

  // ---- P1cd: M2T[s][r] = dec_Wih@M1 ; Q[t][r] = dec_Wih@pre1 + bih + bhh ----
  gemm_rows<DT, 16, false, false>(A.dec_Wih, 1024, 0, 0, wg * 16, M1, M2T, 4096,
                                  nullptr, nullptr, tid, s_big);
  gemm_rows<DT, 16, false, false>(A.dec_Wih, 1024, 0, 0, wg * 16, pre1, Q, 4096,
                                  A.dec_bih, A.dec_bhh, tid, s_big);
  gbar(ws_u, &epoch, tid, wg);

  // ---- preload decoder loop invariants into LDS ----
  for (int i = tid; i < 1024; i += BLK) {
    int l = i >> 6, s = i & 63;
    s_m2[l * 65 + s] = ldw(&M2T[s * 4096 + ((l >> 2) << 10) + j0 + (l & 3)]);
  }
  for (int i = tid; i < 1024; i += BLK) {
    int t = i >> 4, l = i & 15;
    s_q[i] = ldw(&Q[t * 4096 + ((l >> 2) << 10) + j0 + (l & 3)]);
  }
  if (wg < 64) {
    for (int i = tid; i < 1024; i += BLK) s_ep[i] = ldw(&epT[wg * 1024 + i]);
    if (tid < 16) s_av[tid] = LD<DT>::get(A.att_v, wg * 16 + tid);
  }

  // ---- decoder loop: NO grid barriers; h and pe both sentinel-polled ----
  for (int t = 0; t < TL; ++t) {
    { // poll h[64+t]
      const unsigned* hb = (const unsigned*)(hch + (size_t)(64 + t) * HD);
      unsigned uu[4];
#pragma unroll
      for (int j = 0; j < 4; ++j) uu[j] = ldu(hb + tid + j * BLK);
#pragma unroll
      for (int j = 0; j < 4; ++j) {
        while (uu[j] == SENT) { __builtin_amdgcn_s_sleep(1); uu[j] = ldu(hb + tid + j * BLK); }
        float f; __builtin_memcpy(&f, &uu[j], 4);
        s_h[tid + j * BLK] = f;
      }
    }
    __syncthreads();
    // producers first: WGs 0..63 publish attention energies before their Whh matvec
    if (wg < 64) {
      float p2 = 0.f;
#pragma unroll 4
      for (int j = 0; j < 16; ++j) {
        int k = (lane << 2) + (j << 6);
        float4 wv = LD4<DT>::get(A.att_We, (long)(wg * 16 + row_l) * HD + k);
        const float4 hv = *(const float4*)(s_h + k);
        p2 += wv.x * hv.x + wv.y * hv.y + wv.z * hv.z + wv.w * hv.w;
      }
      s_red[tid] = p2;
      __syncthreads();
      if (tid < 16) {
        float v2 = 0.f;
        for (int i = 0; i < 16; ++i) v2 += s_red[tid * 16 + i];
        s_wh[tid] = v2 + LD<DT>::get(A.att_be, wg * 16 + tid);
      }
      __syncthreads();
      if (tid < 64) {
        float pe = 0.f;
#pragma unroll
        for (int jj = 0; jj < 16; ++jj)
          pe += s_av[jj] * tanhf(s_wh[jj] + s_ep[jj * 64 + tid]);
        stw(&peC[(size_t)t * 4096 + wg * 64 + tid], pe);
      }
    }
    // Whh matvec (all WGs) — overlaps other WGs' pe production
    float part = 0.f;
#pragma unroll 4
    for (int j = 0; j < 16; ++j) {
      int k = (lane << 2) + (j << 6);
      float4 wv = LD4<DT>::get(A.dec_Whh, (long)myrow * HD + k);
      const float4 hv = *(const float4*)(s_h + k);
      part += wv.x * hv.x + wv.y * hv.y + wv.z * hv.z + wv.w * hv.w;
    }
    s_red[tid] = part;
    __syncthreads();
    if (tid < 16) {
      float v = 0.f;
      for (int i = 0; i < 16; ++i) v += s_red[tid * 16 + i];
      s_whh[tid] = v;
    }
    __syncthreads();   // protect s_red before pe-phase rewrite
    // phase C: poll all 64 WGs' energy partials (issue all, then fix stragglers)
    {
      int s = tid & 63, gb = tid >> 6;
      const unsigned* pb = (const unsigned*)(peC + (size_t)t * 4096) + s;
      unsigned uu[16];
#pragma unroll
      for (int j = 0; j < 16; ++j) uu[j] = ldu(pb + (gb * 16 + j) * 64);
      float pe = 0.f;
#pragma unroll
      for (int j = 0; j < 16; ++j) {
        while (uu[j] == SENT) { __builtin_amdgcn_s_sleep(1); uu[j] = ldu(pb + (gb * 16 + j) * 64); }
        float f; __builtin_memcpy(&f, &uu[j], 4); pe += f;
      }
      s_red[tid] = pe;
    }
    __syncthreads();
    if (tid < 64) {  // wave-parallel softmax over 64 energies
      float x = s_red[tid] + s_red[64 + tid] + s_red[128 + tid] + s_red[192 + tid];
      float m = x;
#pragma unroll
      for (int d = 32; d >= 1; d >>= 1) m = fmaxf(m, __shfl_xor(m, d, 64));
      float e = expf(x - m);
      float su = e;
#pragma unroll
      for (int d = 32; d >= 1; d >>= 1) su += __shfl_xor(su, d, 64);
      s_w[tid] = e;
      if (tid == 0) s_w[64] = 1.f / su;
    }
    __syncthreads();
    if (tid < 16) {
      float ctx = 0.f;
#pragma unroll 8
      for (int s2 = 0; s2 < 64; ++s2) ctx += s_m2[tid * 65 + s2] * s_w[s2];
      s_gate[tid] = s_whh[tid] + s_q[t * 16 + tid] + ctx * s_w[64];
    }
    __syncthreads();
    if (tid < 4) {
      float ig = s_gate[tid], fg = s_gate[4 + tid], gv = s_gate[8 + tid], og = s_gate[12 + tid];
      float c2 = sigmf(fg) * s_c[tid] + sigmf(ig) * tanhf(gv);
      float h2v = sigmf(og) * tanhf(c2);
      s_c[tid] = c2;
      stw(&hch[(size_t)(65 + t) * HD + j0 + tid], h2v);
    }
  }

  // ---- P2: PreT[j][t] = (w2[:, :H]+w2[:, H:])@H2 + w2_b ; H2 == h chain slots 65..128 ----
  gemm_rows<DT, 4, true, true>(A.w2_W, 2048, 0, 1024, wg * 4, hch + 65 * HD, PreT, 64,
                               A.w2_b, nullptr, tid, s_big);
  gbar(ws_u, &epoch, tid, wg);

  // ---- P3: logits[t][v] = out_W[v].Pre[t] + out_b[v], contiguous v-range per WG ----
  {
    const int t = tid & 63, kq = tid >> 6;
    const int v0 = wg * 125;
    for (int vg = 0; vg < 5; ++vg) {
      float acc[25];
#pragma unroll
      for (int i = 0; i < 25; ++i) acc[i] = 0.f;
      for (int kc = 0; kc < 8; ++kc) {
        __syncthreads();
        for (int i = tid; i < 128 * 64; i += BLK) {
          int kk = i >> 6, tt = i & 63;
          s_big[kk * 66 + tt] = ldw(&PreT[(kc * 128 + kk) * 64 + tt]);
        }
        __syncthreads();
        float p[32];
#pragma unroll
        for (int k = 0; k < 32; ++k) p[k] = s_big[(kq * 32 + k) * 66 + t];
        for (int i = 0; i < 25; ++i) {
          int v = v0 + vg * 25 + i;
          long wb = (long)v * HD + kc * 128 + kq * 32;
          float a = 0.f;
#pragma unroll
          for (int k = 0; k < 32; k += 4) {
            float4 wv = LD4<DT>::get(A.out_W, wb + k);
            a += wv.x * p[k] + wv.y * p[k + 1] + wv.z * p[k + 2] + wv.w * p[k + 3];
          }
          acc[i] += a;
        }
      }
      __syncthreads();
#pragma unroll
      for (int i = 0; i < 25; ++i) s_big[i * 256 + tid] = acc[i];
      __syncthreads();
      for (int o = tid; o < 1600; o += BLK) {
        int tt = o / 25, i = o - tt * 25;
        int v = v0 + vg * 25 + i;
        float r2 = s_big[i * 256 + tt] + s_big[i * 256 + 64 + tt] + s_big[i * 256 + 128 + tt]
                 + s_big[i * 256 + 192 + tt] + LD<DT>::get(A.out_b, v);
        ST<DT>::put(A.out, (long)tt * VOC + v, r2);
      }
      __syncthreads();
    }
  }
}

__global__ __launch_bounds__(BLK)
void lstm_seq2seq_kernel(KArgs A) {
  __shared__ __align__(16) float s_big[8448];   // gemm stage (64*129) / P3 stage (128*66) / P3 acc (25*256)
  __shared__ float s_red[BLK];
  __shared__ float s_w[66];                     // [0..64) softmax weights, [64] = 1/sum
  __shared__ float s_m2[16 * 65];
  __shared__ __align__(16) float s_h[HD];
  __shared__ float s_whh[16];
  __shared__ float s_wh[16];
  __shared__ float s_gate[16];
  __shared__ float s_c[4];
  __shared__ float s_wx[1024];                  // WihX rows for this WG  [64 t][16 l]
  __shared__ float s_q[1024];                   // Q rows for this WG     [64 t][16 l]
  __shared__ float s_ep[1024];                  // epT slice (WGs 0..63)  [16 j][64 s]
  __shared__ float s_av[16];                    // att_v slice (WGs 0..63)
  __shared__ int s_flag;

  const int tid = threadIdx.x, wg = blockIdx.x;

  // dtype probe: bf16 pairs -> low-16 bits look like a bf16 with plausible exponent
  {
    const unsigned* pw = (const unsigned*)A.enc_Wih;
    int hits = 0;
    for (int i = tid; i < 4096; i += BLK) {
      unsigned ex = (pw[i] >> 7) & 0xFFu;
      hits += (ex >= 100u && ex <= 126u) ? 1 : 0;
    }
    s_red[tid] = (float)hits;
    __syncthreads();
    for (int s = BLK / 2; s > 0; s >>= 1) {
      if (tid < s) s_red[tid] += s_red[tid + s];
      __syncthreads();
    }
    if (tid == 0) s_flag = (s_red[0] > 2048.0f) ? 1 : 0;
    __syncthreads();
  }

  if (s_flag) run_all<BFT>(A, tid, wg, s_big, s_red, s_w, s_m2, s_h, s_whh, s_wh, s_gate, s_c,
                           s_wx, s_q, s_ep, s_av);
  else        run_all<FPT>(A, tid, wg, s_big, s_red, s_w, s_m2, s_h, s_whh, s_wh, s_gate, s_c,
                           s_wx, s_q, s_ep, s_av);
}

extern "C" void kernel_launch(void* const* d_in, const int* in_sizes, int n_in,
                              void* d_out, int out_size, void* d_ws, size_t ws_size,
                              hipStream_t stream) {
  (void)in_sizes; (void)n_in; (void)out_size; (void)ws_size;
  // zero barrier counters/flag (sentinel fills are done in-kernel, barrier-protected)
  hipMemsetAsync(d_ws, 0, 256, stream);
  KArgs a;
  a.src = (const int*)d_in[0];
  a.tgt = (const int*)d_in[1];
  a.enc_emb = d_in[3]; a.enc_Wih = d_in[4]; a.enc_Whh = d_in[5];
  a.enc_bih = d_in[6]; a.enc_bhh = d_in[7];
  a.dec_emb = d_in[8]; a.att_We = d_in[9]; a.att_be = d_in[10];
  a.att_Wu = d_in[11]; a.att_bu = d_in[12]; a.att_v = d_in[13];
  a.w1_W = d_in[14]; a.w1_b = d_in[15]; a.w2_W = d_in[16]; a.w2_b = d_in[17];
  a.dec_Wih = d_in[18]; a.dec_Whh = d_in[19]; a.dec_bih = d_in[20]; a.dec_bhh = d_in[21];
  a.out_W = d_in[22]; a.out_b = d_in[23];
  a.out = d_out; a.ws = (float*)d_ws;
  hipLaunchKernelGGL(lstm_seq2seq_kernel, dim3(NWG), dim3(BLK), 0, stream, a);
}

// Round 2
// 2207.020 us; speedup vs baseline: 1.5670x; 1.1243x over previous
//
#include <hip/hip_runtime.h>

#define HD 1024
#define VOC 32000
#define SL 64
#define TL 64
#define NWG 256
#define BLK 256

// sentinel NaN used for dataflow sync; never produced by the math
// (h = sigm*tanh in (-1,1); pe bounded sums of v*tanh)
#define SENT 0x7FC0DEADu

// ---- workspace float offsets ----
// [0..64): barrier words (zeroed by hipMemsetAsync each launch)
#define OFF_HCH    4096      // h chain [129][1024]: enc h_t at slot t (slot 0 unused: h0==0), dec h at 64+t
#define OFF_EPT    139264    // epT [1024][64]  (enc_proj transposed)
#define OFF_WIHX   204800    // WihX [64][4096] (enc phase) -- region reused as pe chain [64][4096] (dec phase)
#define OFF_PE     OFF_WIHX
#define OFF_Q      466944    // Q    [64][4096]
#define OFF_M1     729088    // M1   [64][1024]
#define OFF_M2     794624    // M2T  [64][4096]
#define OFF_PRET   1056768   // PreT [1024][64]
#define OFF_XENC   1122304   // Xenc [64][1024]
#define OFF_XDEC   1187840   // Xdec [64][1024]
#define OFF_PRE1   1253376   // pre1 [64][1024]

struct KArgs {
  const int* src; const int* tgt;
  const void *enc_emb, *enc_Wih, *enc_Whh, *enc_bih, *enc_bhh;
  const void *dec_emb, *att_We, *att_be, *att_Wu, *att_bu, *att_v;
  const void *w1_W, *w1_b, *w2_W, *w2_b;
  const void *dec_Wih, *dec_Whh, *dec_bih, *dec_bhh;
  const void *out_W, *out_b;
  void* out; float* ws;
};

__device__ __forceinline__ float bf2f(unsigned short u) {
  unsigned w = ((unsigned)u) << 16; float f; __builtin_memcpy(&f, &w, 4); return f;
}
__device__ __forceinline__ unsigned short f2bf(float f) {
  unsigned u; __builtin_memcpy(&u, &f, 4);
  unsigned r = u + 0x7FFFu + ((u >> 16) & 1u);
  return (unsigned short)(r >> 16);
}
__device__ __forceinline__ float sigmf(float x) { return 1.f / (1.f + expf(-x)); }

// MALL-coherent (cross-XCD) relaxed accesses for all workspace traffic.
__device__ __forceinline__ float ldw(const float* p) {
  return __hip_atomic_load(p, __ATOMIC_RELAXED, __HIP_MEMORY_SCOPE_AGENT);
}
__device__ __forceinline__ void stw(float* p, float v) {
  __hip_atomic_store(p, v, __ATOMIC_RELAXED, __HIP_MEMORY_SCOPE_AGENT);
}
__device__ __forceinline__ unsigned ldu(const unsigned* p) {
  return __hip_atomic_load(p, __ATOMIC_RELAXED, __HIP_MEMORY_SCOPE_AGENT);
}
__device__ __forceinline__ void stu(unsigned* p, unsigned v) {
  __hip_atomic_store(p, v, __ATOMIC_RELAXED, __HIP_MEMORY_SCOPE_AGENT);
}

// parallel-sweep sentinel poll: re-issue ALL N loads concurrently each sweep.
// Cost per sweep = one MALL round trip, not N dependent ones.
template<int N>
__device__ __forceinline__ void sweep_poll(const unsigned* base, int stride, unsigned* uu) {
#pragma unroll
  for (int j = 0; j < N; ++j) uu[j] = ldu(base + j * stride);
  for (;;) {
    bool need = false;
#pragma unroll
    for (int j = 0; j < N; ++j) need |= (uu[j] == SENT);
    if (!need) return;
    __builtin_amdgcn_s_sleep(1);
#pragma unroll
    for (int j = 0; j < N; ++j) uu[j] = ldu(base + j * stride);
  }
}

struct BFT {}; struct FPT {};
template<class DT> struct LD;
template<> struct LD<FPT> {
  static __device__ __forceinline__ float get(const void* p, long i) { return ((const float*)p)[i]; }
};
template<> struct LD<BFT> {
  static __device__ __forceinline__ float get(const void* p, long i) { return bf2f(((const unsigned short*)p)[i]); }
};
template<class DT> struct LD4;
template<> struct LD4<FPT> {
  static __device__ __forceinline__ float4 get(const void* p, long i) {
    return *(const float4*)((const float*)p + i);
  }
};
template<> struct LD4<BFT> {
  static __device__ __forceinline__ float4 get(const void* p, long i) {
    ushort4 u = *(const ushort4*)((const unsigned short*)p + i);
    float4 f; f.x = bf2f(u.x); f.y = bf2f(u.y); f.z = bf2f(u.z); f.w = bf2f(u.w); return f;
  }
};
template<class DT> struct ST;
template<> struct ST<FPT> {
  static __device__ __forceinline__ void put(void* p, long i, float v) { ((float*)p)[i] = v; }
};
template<> struct ST<BFT> {
  static __device__ __forceinline__ void put(void* p, long i, float v) { ((unsigned short*)p)[i] = f2bf(v); }
};

// ---- tree grid barrier (phase transitions only; 5 calls total) ----
__device__ __forceinline__ void gbar(unsigned* ws_u, unsigned* ep, int tid, int wg) {
  __syncthreads();
  if (tid == 0) {
    unsigned e = ++(*ep);
    unsigned old = __hip_atomic_fetch_add(&ws_u[8 + (wg >> 5)], 1u,
                                          __ATOMIC_RELAXED, __HIP_MEMORY_SCOPE_AGENT);
    if (old == e * 32u - 1u) {
      unsigned o2 = __hip_atomic_fetch_add(&ws_u[16], 1u,
                                           __ATOMIC_RELAXED, __HIP_MEMORY_SCOPE_AGENT);
      if (o2 == e * 8u - 1u) {
        __hip_atomic_store(&ws_u[20], e, __ATOMIC_RELAXED, __HIP_MEMORY_SCOPE_AGENT);
      }
    }
    while (__hip_atomic_load(&ws_u[20], __ATOMIC_RELAXED, __HIP_MEMORY_SCOPE_AGENT) < e) {
      __builtin_amdgcn_s_sleep(2);
    }
  }
  __syncthreads();
}

// out[t][r] (or [r][t] if TRO) = sum_k W[r*wstride+woff+k] (+ woff2 half if DUAL) * X[t*HD+k] (+biases)
template<class DT, int NR, bool DUAL, bool TRO>
__device__ void gemm_rows(const void* W, int wstride, int woff, int woff2,
                          int r0, const float* X, float* out, int ostride,
                          const void* b1, const void* b2, int tid, float* s_stage) {
  const int PER = NR / 4;
  float acc[PER];
#pragma unroll
  for (int i = 0; i < PER; ++i) acc[i] = 0.f;
  for (int k0 = 0; k0 < HD; k0 += 128) {
    __syncthreads();
    for (int i = tid; i < 64 * 128; i += BLK) {
      int t = i >> 7, kk = i & 127;
      s_stage[t * 129 + kk] = ldw(&X[t * HD + k0 + kk]);
    }
    __syncthreads();
#pragma unroll
    for (int i = 0; i < PER; ++i) {
      int oi = tid + i * BLK;
      int t = oi & 63, r_l = oi >> 6;
      long r = r0 + r_l;
      long wb = r * wstride + woff + k0;
      long wb2 = r * wstride + woff2 + k0;
      float a = 0.f;
#pragma unroll 8
      for (int kk = 0; kk < 128; kk += 4) {
        float4 wv = LD4<DT>::get(W, wb + kk);
        if (DUAL) {
          float4 w2 = LD4<DT>::get(W, wb2 + kk);
          wv.x += w2.x; wv.y += w2.y; wv.z += w2.z; wv.w += w2.w;
        }
        a += wv.x * s_stage[t * 129 + kk]     + wv.y * s_stage[t * 129 + kk + 1]
           + wv.z * s_stage[t * 129 + kk + 2] + wv.w * s_stage[t * 129 + kk + 3];
      }
      acc[i] += a;
    }
  }
  __syncthreads();
#pragma unroll
  for (int i = 0; i < PER; ++i) {
    int oi = tid + i * BLK;
    int t = oi & 63, r_l = oi >> 6;
    int r = r0 + r_l;
    float v = acc[i];
    if (b1) v += LD<DT>::get(b1, r);
    if (b2) v += LD<DT>::get(b2, r);
    if (TRO) stw(&out[r * ostride + t], v); else stw(&out[t * ostride + r], v);
  }
}

template<class DT>
__device__ void run_all(const KArgs& A, int tid, int wg,
                        float* s_big, float* s_red, float* s_w, float* s_m2,
                        float* s_h, float* s_whh, float* s_wh, float* s_gate, float* s_c,
                        float* s_wx, float* s_q, float* s_ep, float* s_av) {
  float* ws = A.ws;
  unsigned* ws_u = (unsigned*)ws;
  unsigned epoch = 0;
  float* hch   = ws + OFF_HCH;
  float* epT   = ws + OFF_EPT;
  float* WihX  = ws + OFF_WIHX;
  float* peC   = ws + OFF_PE;     // same region as WihX; only valid in decoder phase
  float* Q     = ws + OFF_Q;
  float* M1    = ws + OFF_M1;
  float* M2T   = ws + OFF_M2;
  float* PreT  = ws + OFF_PRET;
  float* Xenc  = ws + OFF_XENC;
  float* Xdec  = ws + OFF_XDEC;
  float* pre1  = ws + OFF_PRE1;
  const int j0 = wg * 4;

  // ---- P0a: sentinel-fill h chain, embedding gathers, zero c ----
  if (tid < 4) s_c[tid] = 0.f;
  {
    unsigned* hu = (unsigned*)hch;
    for (int i = wg * BLK + tid; i < 129 * 1024; i += NWG * BLK) stu(hu + i, SENT);
  }
  if (wg < 64) {
    int t = wg, tok = A.src[t];
    for (int k = tid; k < HD; k += BLK) stw(&Xenc[t * HD + k], LD<DT>::get(A.enc_emb, (long)tok * HD + k));
  } else if (wg < 128) {
    int t = wg - 64;
    int tok = (t == 0) ? 0 : A.tgt[t - 1];
    for (int k = tid; k < HD; k += BLK) stw(&Xdec[t * HD + k], LD<DT>::get(A.dec_emb, (long)tok * HD + k));
  }
  gbar(ws_u, &epoch, tid, wg);

  // ---- P0b: WihX (enc_Wih@x + bih + bhh), pre1 (W1x@x + w1_b) ----
  gemm_rows<DT, 16, false, false>(A.enc_Wih, 1024, 0, 0, wg * 16, Xenc, WihX, 4096,
                                  A.enc_bih, A.enc_bhh, tid, s_big);
  gemm_rows<DT, 4, false, false>(A.w1_W, 2048, 1024, 0, wg * 4, Xdec, pre1, 1024,
                                 A.w1_b, nullptr, tid, s_big);
  gbar(ws_u, &epoch, tid, wg);

  // ---- preload this WG's 16 WihX rows x 64 t into LDS (WihX never read again) ----
  for (int i = tid; i < 1024; i += BLK) {
    int t = i >> 4, l = i & 15;
    s_wx[i] = ldw(&WihX[t * 4096 + ((l >> 2) << 10) + j0 + (l & 3)]);
  }

  const int row_l = tid >> 4, lane = tid & 15;
  const int gg_ = row_l >> 2, qq_ = row_l & 3;
  const int myrow = gg_ * 1024 + j0 + qq_;

  // ---- register-cache enc_Whh rows for this thread (critical path of every enc step) ----
  float4 wrec[16];
#pragma unroll
  for (int j = 0; j < 16; ++j)
    wrec[j] = LD4<DT>::get(A.enc_Whh, (long)myrow * HD + (lane << 2) + (j << 6));

  // ---- encoder loop: no grid barriers; h[t] parallel-sweep-polled ----
  for (int t = 0; t < SL; ++t) {
    if (t == 0) {
      for (int i = tid; i < HD; i += BLK) s_h[i] = 0.f;
    } else {
      const unsigned* hb = (const unsigned*)(hch + (size_t)t * HD);
      unsigned uu[4];
      sweep_poll<4>(hb + tid, BLK, uu);
#pragma unroll
      for (int j = 0; j < 4; ++j) { float f; __builtin_memcpy(&f, &uu[j], 4); s_h[tid + j * BLK] = f; }
    }
    __syncthreads();
    float part = 0.f;
#pragma unroll
    for (int j = 0; j < 16; ++j) {
      const float4 hv = *(const float4*)(s_h + (lane << 2) + (j << 6));
      part += wrec[j].x * hv.x + wrec[j].y * hv.y + wrec[j].z * hv.z + wrec[j].w * hv.w;
    }
#pragma unroll
    for (int d = 8; d >= 1; d >>= 1) part += __shfl_xor(part, d, 64);
    if ((tid & 15) == 0) s_red[row_l] = part + s_wx[t * 16 + row_l];
    __syncthreads();
    if (tid < 4) {
      float ig = s_red[tid], fg = s_red[4 + tid], gv = s_red[8 + tid], og = s_red[12 + tid];
      float c2 = sigmf(fg) * s_c[tid] + sigmf(ig) * tanhf(gv);
      float h2v = sigmf(og) * tanhf(c2);
      s_c[tid] = c2;
      stw(&hch[(size_t)(t + 1) * HD + j0 + tid], h2v);
    }
  }

  // ensure slot 64 (enc_out[63], written by OTHER WGs' step 63) fully arrived before P1 gemms
  {
    unsigned uu[4];
    sweep_poll<4>((const unsigned*)(hch + (size_t)64 * HD) + tid, BLK, uu);
  }

  // ---- P1ab: epT = (att_Wu@enc_outs + bu)^T ; M1[s][j] = W1c[j].enc_outs[s] ----
  gemm_rows<DT, 4, false, true>(A.att_Wu, 1024, 0, 0, wg * 4, hch + HD, epT, 64,
                                A.att_bu, nullptr, tid, s_big);
  gemm_rows<DT, 4, false, false>(A.w1_W, 2048, 0, 0, wg * 4, hch + HD, M1, 1024,
                                 nullptr, nullptr, tid, s_big);
  // sentinel-fill pe chain (reuses WihX region; WihX fully consumed into s_wx)
  {
    unsigned* pu = (unsigned*)peC;
    for (int i = tid; i < 1024; i += BLK) stu(pu + wg * 1024 + i, SENT);
  }
  gbar(ws_u, &epoch, tid, wg);

  // ---- P1cd: M2T[s][r] = dec_Wih@M1 ; Q[t][r] = dec_Wih@pre1 + bih + bhh ----
  gemm_rows<DT, 16, false, false>(A.dec_Wih, 1024, 0, 0, wg * 16, M1, M2T, 4096,
                                  nullptr, nullptr, tid, s_big);
  gemm_rows<DT, 16, false, false>(A.dec_Wih, 1024, 0, 0, wg * 16, pre1, Q, 4096,
                                  A.dec_bih, A.dec_bhh, tid, s_big);
  gbar(ws_u, &epoch, tid, wg);

  // ---- preload decoder loop invariants ----
  for (int i = tid; i < 1024; i += BLK) {
    int l = i >> 6, s = i & 63;
    s_m2[l * 65 + s] = ldw(&M2T[s * 4096 + ((l >> 2) << 10) + j0 + (l & 3)]);
  }
  for (int i = tid; i < 1024; i += BLK) {
    int t = i >> 4, l = i & 15;
    s_q[i] = ldw(&Q[t * 4096 + ((l >> 2) << 10) + j0 + (l & 3)]);
  }
  if (wg < 64) {
    for (int i = tid; i < 1024; i += BLK) s_ep[i] = ldw(&epT[wg * 1024 + i]);
    if (tid < 16) s_av[tid] = LD<DT>::get(A.att_v, wg * 16 + tid);
  }
  // register-cache att_We rows (pe-producer critical path, WGs 0..63)
  float4 wwe[16];
  if (wg < 64) {
#pragma unroll
    for (int j = 0; j < 16; ++j)
      wwe[j] = LD4<DT>::get(A.att_We, (long)(wg * 16 + row_l) * HD + (lane << 2) + (j << 6));
  }

  // ---- decoder loop: no grid barriers; h and pe parallel-sweep-polled ----
  for (int t = 0; t < TL; ++t) {
    { // poll h[64+t]
      const unsigned* hb = (const unsigned*)(hch + (size_t)(64 + t) * HD);
      unsigned uu[4];
      sweep_poll<4>(hb + tid, BLK, uu);
#pragma unroll
      for (int j = 0; j < 4; ++j) { float f; __builtin_memcpy(&f, &uu[j], 4); s_h[tid + j * BLK] = f; }
    }
    __syncthreads();
    // producers first: WGs 0..63 publish attention energies (critical path)
    if (wg < 64) {
      float p2 = 0.f;
#pragma unroll
      for (int j = 0; j < 16; ++j) {
        const float4 hv = *(const float4*)(s_h + (lane << 2) + (j << 6));
        p2 += wwe[j].x * hv.x + wwe[j].y * hv.y + wwe[j].z * hv.z + wwe[j].w * hv.w;
      }
#pragma unroll
      for (int d = 8; d >= 1; d >>= 1) p2 += __shfl_xor(p2, d, 64);
      if ((tid & 15) == 0) s_wh[row_l] = p2 + LD<DT>::get(A.att_be, wg * 16 + row_l);
      __syncthreads();
      if (tid < 64) {
        float pe = 0.f;
#pragma unroll
        for (int jj = 0; jj < 16; ++jj)
          pe += s_av[jj] * tanhf(s_wh[jj] + s_ep[jj * 64 + tid]);
        stw(&peC[(size_t)t * 4096 + wg * 64 + tid], pe);
      }
    }
    // issue first pe sweep's loads early (latency hides under Whh matvec)
    const int s_ = tid & 63, gb = tid >> 6;
    const unsigned* pb = (const unsigned*)(peC + (size_t)t * 4096) + s_;
    unsigned uu[16];
#pragma unroll
    for (int j = 0; j < 16; ++j) uu[j] = ldu(pb + (gb * 16 + j) * 64);
    // Whh matvec (all WGs; off pe critical path, weights from L2)
    float part = 0.f;
#pragma unroll
    for (int j = 0; j < 16; ++j) {
      int k = (lane << 2) + (j << 6);
      float4 wv = LD4<DT>::get(A.dec_Whh, (long)myrow * HD + k);
      const float4 hv = *(const float4*)(s_h + k);
      part += wv.x * hv.x + wv.y * hv.y + wv.z * hv.z + wv.w * hv.w;
    }
#pragma unroll
    for (int d = 8; d >= 1; d >>= 1) part += __shfl_xor(part, d, 64);
    if ((tid & 15) == 0) s_whh[row_l] = part;
    // pe sweep: parallel re-issue of all 16 until complete
    for (;;) {
      bool need = false;
#pragma unroll
      for (int j = 0; j < 16; ++j) need |= (uu[j] == SENT);
      if (!need) break;
      __builtin_amdgcn_s_sleep(1);
#pragma unroll
      for (int j = 0; j < 16; ++j) uu[j] = ldu(pb + (gb * 16 + j) * 64);
    }
    float pe = 0.f;
#pragma unroll
    for (int j = 0; j < 16; ++j) { float f; __builtin_memcpy(&f, &uu[j], 4); pe += f; }
    s_red[tid] = pe;
    __syncthreads();
    if (tid < 64) {  // wave-parallel softmax over 64 energies
      float x = s_red[tid] + s_red[64 + tid] + s_red[128 + tid] + s_red[192 + tid];
      float m = x;
#pragma unroll
      for (int d = 32; d >= 1; d >>= 1) m = fmaxf(m, __shfl_xor(m, d, 64));
      float e = expf(x - m);
      float su = e;
#pragma unroll
      for (int d = 32; d >= 1; d >>= 1) su += __shfl_xor(su, d, 64);
      s_w[tid] = e;
      if (tid == 0) s_w[64] = 1.f / su;
    }
    __syncthreads();
    // ctx: 4 threads per gate-row, shfl-combined (wave 0)
    float ctxp = 0.f;
    if (tid < 64) {
      int l = tid & 15, g = tid >> 4;
#pragma unroll
      for (int s2 = g * 16; s2 < g * 16 + 16; ++s2) ctxp += s_m2[l * 65 + s2] * s_w[s2];
      ctxp += __shfl_xor(ctxp, 16, 64);
      ctxp += __shfl_xor(ctxp, 32, 64);
    }
    if (tid < 16) s_gate[tid] = s_whh[tid] + s_q[t * 16 + tid] + ctxp * s_w[64];
    __syncthreads();
    if (tid < 4) {
      float ig = s_gate[tid], fg = s_gate[4 + tid], gv = s_gate[8 + tid], og = s_gate[12 + tid];
      float c2 = sigmf(fg) * s_c[tid] + sigmf(ig) * tanhf(gv);
      float h2v = sigmf(og) * tanhf(c2);
      s_c[tid] = c2;
      stw(&hch[(size_t)(65 + t) * HD + j0 + tid], h2v);
    }
  }

  // ensure slot 128 (dec h2[63], written by OTHER WGs) fully arrived before P2
  {
    unsigned uu[4];
    sweep_poll<4>((const unsigned*)(hch + (size_t)128 * HD) + tid, BLK, uu);
  }

  // ---- P2: PreT[j][t] = (w2[:, :H]+w2[:, H:])@H2 + w2_b ; H2 == h chain slots 65..128 ----
  gemm_rows<DT, 4, true, true>(A.w2_W, 2048, 0, 1024, wg * 4, hch + 65 * HD, PreT, 64,
                               A.w2_b, nullptr, tid, s_big);
  gbar(ws_u, &epoch, tid, wg);

  // ---- P3: logits[t][v] = out_W[v].Pre[t] + out_b[v], contiguous v-range per WG ----
  {
    const int t = tid & 63, kq = tid >> 6;
    const int v0 = wg * 125;
    for (int vg = 0; vg < 5; ++vg) {
      float acc[25];
#pragma unroll
      for (int i = 0; i < 25; ++i) acc[i] = 0.f;
      for (int kc = 0; kc < 8; ++kc) {
        __syncthreads();
        for (int i = tid; i < 128 * 64; i += BLK) {
          int kk = i >> 6, tt = i & 63;
          s_big[kk * 66 + tt] = ldw(&PreT[(kc * 128 + kk) * 64 + tt]);
        }
        __syncthreads();
        float p[32];
#pragma unroll
        for (int k = 0; k < 32; ++k) p[k] = s_big[(kq * 32 + k) * 66 + t];
        for (int i = 0; i < 25; ++i) {
          int v = v0 + vg * 25 + i;
          long wb = (long)v * HD + kc * 128 + kq * 32;
          float a = 0.f;
#pragma unroll
          for (int k = 0; k < 32; k += 4) {
            float4 wv = LD4<DT>::get(A.out_W, wb + k);
            a += wv.x * p[k] + wv.y * p[k + 1] + wv.z * p[k + 2] + wv.w * p[k + 3];
          }
          acc[i] += a;
        }
      }
      __syncthreads();
#pragma unroll
      for (int i = 0; i < 25; ++i) s_big[i * 256 + tid] = acc[i];
      __syncthreads();
      for (int o = tid; o < 1600; o += BLK) {
        int tt = o / 25, i = o - tt * 25;
        int v = v0 + vg * 25 + i;
        float r2 = s_big[i * 256 + tt] + s_big[i * 256 + 64 + tt] + s_big[i * 256 + 128 + tt]
                 + s_big[i * 256 + 192 + tt] + LD<DT>::get(A.out_b, v);
        ST<DT>::put(A.out, (long)tt * VOC + v, r2);
      }
      __syncthreads();
    }
  }
}

__global__ __launch_bounds__(BLK)
void lstm_seq2seq_kernel(KArgs A) {
  __shared__ __align__(16) float s_big[8448];   // gemm stage (64*129) / P3 stage (128*66) / P3 acc (25*256)
  __shared__ float s_red[BLK];
  __shared__ float s_w[66];                     // [0..64) softmax weights, [64] = 1/sum
  __shared__ float s_m2[16 * 65];
  __shared__ __align__(16) float s_h[HD];
  __shared__ float s_whh[16];
  __shared__ float s_wh[16];
  __shared__ float s_gate[16];
  __shared__ float s_c[4];
  __shared__ float s_wx[1024];                  // WihX rows for this WG  [64 t][16 l]
  __shared__ float s_q[1024];                   // Q rows for this WG     [64 t][16 l]
  __shared__ float s_ep[1024];                  // epT slice (WGs 0..63)  [16 j][64 s]
  __shared__ float s_av[16];                    // att_v slice (WGs 0..63)
  __shared__ int s_flag;

  const int tid = threadIdx.x, wg = blockIdx.x;

  // dtype probe: bf16 pairs -> low-16 bits look like a bf16 with plausible exponent
  {
    const unsigned* pw = (const unsigned*)A.enc_Wih;
    int hits = 0;
    for (int i = tid; i < 4096; i += BLK) {
      unsigned ex = (pw[i] >> 7) & 0xFFu;
      hits += (ex >= 100u && ex <= 126u) ? 1 : 0;
    }
    s_red[tid] = (float)hits;
    __syncthreads();
    for (int s = BLK / 2; s > 0; s >>= 1) {
      if (tid < s) s_red[tid] += s_red[tid + s];
      __syncthreads();
    }
    if (tid == 0) s_flag = (s_red[0] > 2048.0f) ? 1 : 0;
    __syncthreads();
  }

  if (s_flag) run_all<BFT>(A, tid, wg, s_big, s_red, s_w, s_m2, s_h, s_whh, s_wh, s_gate, s_c,
                           s_wx, s_q, s_ep, s_av);
  else        run_all<FPT>(A, tid, wg, s_big, s_red, s_w, s_m2, s_h, s_whh, s_wh, s_gate, s_c,
                           s_wx, s_q, s_ep, s_av);
}

extern "C" void kernel_launch(void* const* d_in, const int* in_sizes, int n_in,
                              void* d_out, int out_size, void* d_ws, size_t ws_size,
                              hipStream_t stream) {
  (void)in_sizes; (void)n_in; (void)out_size; (void)ws_size;
  // zero barrier counters/flag (sentinel fills are done in-kernel, barrier-protected)
  hipMemsetAsync(d_ws, 0, 256, stream);
  KArgs a;
  a.src = (const int*)d_in[0];
  a.tgt = (const int*)d_in[1];
  a.enc_emb = d_in[3]; a.enc_Wih = d_in[4]; a.enc_Whh = d_in[5];
  a.enc_bih = d_in[6]; a.enc_bhh = d_in[7];
  a.dec_emb = d_in[8]; a.att_We = d_in[9]; a.att_be = d_in[10];
  a.att_Wu = d_in[11]; a.att_bu = d_in[12]; a.att_v = d_in[13];
  a.w1_W = d_in[14]; a.w1_b = d_in[15]; a.w2_W = d_in[16]; a.w2_b = d_in[17];
  a.dec_Wih = d_in[18]; a.dec_Whh = d_in[19]; a.dec_bih = d_in[20]; a.dec_bhh = d_in[21];
  a.out_W = d_in[22]; a.out_b = d_in[23];
  a.out = d_out; a.ws = (float*)d_ws;
  hipLaunchKernelGGL(lstm_seq2seq_kernel, dim3(NWG), dim3(BLK), 0, stream, a);
}